// Round 1
// baseline (294.930 us; speedup 1.0000x reference)
//
#include <hip/hip_runtime.h>

// Problem constants from the reference
static constexpr int B = 4096;
static constexpr int T = 200;
static constexpr int A = 64;

// One block per batch row b. Threads t<T gather policies[b,t,actions[b,t]],
// take log, block-reduce the sum over T, scale by (ea[b]-adv[b])/B, and
// atomically accumulate into out[0].
__global__ __launch_bounds__(256) void multiloss_kernel(
    const float* __restrict__ policies,   // [B*T*A]
    const int*   __restrict__ actions,    // [B*T] (int32; jax x64 disabled)
    const float* __restrict__ ea,         // [B]
    const float* __restrict__ adv,        // [B]
    float* __restrict__ out)              // [1]
{
    const int b = blockIdx.x;
    const int t = threadIdx.x;

    float v = 0.0f;
    if (t < T) {
        const int idx = b * T + t;
        const int a = actions[idx];
        const float p = policies[(long long)idx * A + a];
        v = __logf(p);
    }

    // wave (64-lane) shuffle reduction
    #pragma unroll
    for (int off = 32; off > 0; off >>= 1)
        v += __shfl_down(v, off, 64);

    __shared__ float ws[4];
    const int lane = threadIdx.x & 63;
    const int wid  = threadIdx.x >> 6;
    if (lane == 0) ws[wid] = v;
    __syncthreads();

    if (threadIdx.x == 0) {
        const float s = ws[0] + ws[1] + ws[2] + ws[3];
        const float pe = s * (ea[b] - adv[b]) * (1.0f / (float)B);
        atomicAdd(out, pe);
    }
}

extern "C" void kernel_launch(void* const* d_in, const int* in_sizes, int n_in,
                              void* d_out, int out_size, void* d_ws, size_t ws_size,
                              hipStream_t stream) {
    const float* policies = (const float*)d_in[0];
    const int*   actions  = (const int*)d_in[1];
    const float* ea       = (const float*)d_in[2];
    const float* adv      = (const float*)d_in[3];
    float* out = (float*)d_out;

    // d_out is poisoned (0xAA) before every timed launch — zero it first.
    hipMemsetAsync(out, 0, sizeof(float), stream);

    multiloss_kernel<<<B, 256, 0, stream>>>(policies, actions, ea, adv, out);
}

// Round 2
// 268.131 us; speedup vs baseline: 1.0999x; 1.0999x over previous
//
#include <hip/hip_runtime.h>

// Problem constants from the reference
static constexpr int B = 4096;
static constexpr int T = 200;
static constexpr int A = 64;
static constexpr int N = B * T;          // 819,200 gathered elements
static constexpr int VEC = 4;            // elements per thread
static constexpr int BLOCK = 256;
static constexpr int GRID1 = N / (BLOCK * VEC);   // 800 blocks, exact

// loss = (1/B) * sum_{b,t} (ea[b]-adv[b]) * log(policies[b,t,actions[b,t]])
// Stage 1: flat sum, one partial per block -> ws[blockIdx]
__global__ __launch_bounds__(BLOCK) void multiloss_partial(
    const float* __restrict__ policies,   // [B*T*A]
    const int*   __restrict__ actions,    // [B*T] (int32; jax x64 disabled)
    const float* __restrict__ ea,         // [B]
    const float* __restrict__ adv,        // [B]
    float* __restrict__ ws)               // [GRID1] partials
{
    const int tid = blockIdx.x * BLOCK + threadIdx.x;
    const int g0  = tid * VEC;

    // coalesced 16B action load
    const int4 a4 = ((const int4*)actions)[tid];
    const int a[VEC] = {a4.x, a4.y, a4.z, a4.w};

    float acc = 0.0f;
    #pragma unroll
    for (int k = 0; k < VEC; ++k) {
        const int g = g0 + k;
        const int b = g / T;                         // magic-mul division
        const float p = policies[(long long)g * A + a[k]];
        const float coef = ea[b] - adv[b];           // L2-cached, high reuse
        acc += __logf(p) * coef;
    }

    // wave (64-lane) butterfly reduction
    #pragma unroll
    for (int off = 32; off > 0; off >>= 1)
        acc += __shfl_down(acc, off, 64);

    __shared__ float red[4];
    const int lane = threadIdx.x & 63;
    const int wid  = threadIdx.x >> 6;
    if (lane == 0) red[wid] = acc;
    __syncthreads();
    if (threadIdx.x == 0)
        ws[blockIdx.x] = red[0] + red[1] + red[2] + red[3];
}

// Stage 2: one block reduces GRID1 partials, writes out[0] = total / B
__global__ __launch_bounds__(BLOCK) void multiloss_final(
    const float* __restrict__ ws,
    float* __restrict__ out)
{
    float acc = 0.0f;
    for (int i = threadIdx.x; i < GRID1; i += BLOCK)
        acc += ws[i];

    #pragma unroll
    for (int off = 32; off > 0; off >>= 1)
        acc += __shfl_down(acc, off, 64);

    __shared__ float red[4];
    const int lane = threadIdx.x & 63;
    const int wid  = threadIdx.x >> 6;
    if (lane == 0) red[wid] = acc;
    __syncthreads();
    if (threadIdx.x == 0)
        out[0] = (red[0] + red[1] + red[2] + red[3]) * (1.0f / (float)B);
}

extern "C" void kernel_launch(void* const* d_in, const int* in_sizes, int n_in,
                              void* d_out, int out_size, void* d_ws, size_t ws_size,
                              hipStream_t stream) {
    const float* policies = (const float*)d_in[0];
    const int*   actions  = (const int*)d_in[1];
    const float* ea       = (const float*)d_in[2];
    const float* adv      = (const float*)d_in[3];
    float* out = (float*)d_out;
    float* ws  = (float*)d_ws;

    multiloss_partial<<<GRID1, BLOCK, 0, stream>>>(policies, actions, ea, adv, ws);
    multiloss_final<<<1, BLOCK, 0, stream>>>(ws, out);
}